// Round 1
// 441.432 us; speedup vs baseline: 1.0630x; 1.0630x over previous
//
#include <hip/hip_runtime.h>
#include <hip/hip_bf16.h>

// Problem dims (fixed by reference):
//   x:  [B=16, c_in=64, T=64, N=512] fp32
//   La: [B=16, N=512, N=512] fp32
//   W:  [c_out=64, K*c_in=192] fp32
//   out:[B, 64, T, N] fp32
// Math: out[b,o,t,q] = sum_{c,k} W[o, c*3+k] * z_k[b,c,t,q]
//   z0 = x ; z1 = X @ La^T (rows ct, reduce n) ; z2 = 2*(z1 @ La^T) - x

#define B_   16
#define CIN  64
#define T_   64
#define N_   512
#define M_   4096   // CIN*T_ rows per batch
#define KDIM 512
#define COUT 64

typedef __bf16 bf16x8 __attribute__((ext_vector_type(8)));
typedef float  floatx4 __attribute__((ext_vector_type(4)));
typedef unsigned int uintx4 __attribute__((ext_vector_type(4)));

__device__ __forceinline__ float bf2f(unsigned short u) {
    unsigned int v = ((unsigned int)u) << 16;
    return __builtin_bit_cast(float, v);
}
__device__ __forceinline__ unsigned short f2bf(float f) {
    unsigned int u = __builtin_bit_cast(unsigned int, f);
    unsigned int lsb = (u >> 16) & 1u;
    u += 0x7fffu + lsb;           // round-to-nearest-even
    return (unsigned short)(u >> 16);
}

// async global->LDS, 16B per lane; LDS dest = wave-uniform base + lane*16
#define GLOAD_LDS16(gp, lp)                                                  \
    __builtin_amdgcn_global_load_lds(                                        \
        (const __attribute__((address_space(1))) void*)(gp),                 \
        (__attribute__((address_space(3))) void*)(lp), 16, 0, 0)

// ---- K0a/K0b: fp32 -> bf16 convert, 8 elems/thread ----
__global__ __launch_bounds__(256) void cvt_f32_bf16(
    const float* __restrict__ src, unsigned short* __restrict__ dst, int n)
{
    int i = (blockIdx.x * 256 + threadIdx.x) * 8;
    if (i + 8 <= n) {
        float4 a = *(const float4*)(src + i);
        float4 b = *(const float4*)(src + i + 4);
        union { unsigned short s[8]; uint4 u; } o;
        o.s[0] = f2bf(a.x); o.s[1] = f2bf(a.y); o.s[2] = f2bf(a.z); o.s[3] = f2bf(a.w);
        o.s[4] = f2bf(b.x); o.s[5] = f2bf(b.y); o.s[6] = f2bf(b.z); o.s[7] = f2bf(b.w);
        *(uint4*)(dst + i) = o.u;
    }
}

// ---- K0c: repack W[o][c*3+k] -> Wb[o][j=k*64+c] bf16 (A-operand layout) ----
__global__ __launch_bounds__(256) void pack_w(
    const float* __restrict__ W, unsigned short* __restrict__ Wb)
{
    int idx = threadIdx.x + blockIdx.x * 256;   // idx = o*192 + j
    if (idx < 64 * 192) {
        int o = idx / 192, j = idx % 192;
        int c = j & 63, k = j >> 6;
        Wb[idx] = f2bf(W[o * 192 + c * 3 + k]);
    }
}

// ---- K1/K2: batched bf16 NT-GEMM  C[m][q] = sum_n A[m][n]*Bm[q][n] ----
// v2: triple-buffered LDS + counted s_waitcnt vmcnt(4) + raw s_barrier.
// Prefetch distance 2: tiles k, k+1 always in flight across the barrier;
// vmcnt is never drained to 0 in the main loop (T3/T4 minimum recipe).
#define BM 128
#define BN 128
#define BK 32
#define KIT  (KDIM / BK)     // 16 K-steps
#define SBUF (BM * BK)       // 4096 ushorts per buffer per matrix

__global__ __launch_bounds__(256) void gemm_bt(
    const unsigned short* __restrict__ A,
    const unsigned short* __restrict__ Bm,
    unsigned short* __restrict__ C,
    const unsigned short* __restrict__ X,
    int mode)
{
    int batch = blockIdx.z;
    A  += (size_t)batch * M_ * KDIM;
    Bm += (size_t)batch * N_ * KDIM;
    C  += (size_t)batch * M_ * N_;
    X  += (size_t)batch * M_ * N_;
    int m0 = blockIdx.y * BM;
    int n0 = blockIdx.x * BN;

    __shared__ __align__(16) unsigned short As[3 * SBUF];   // 24 KB
    __shared__ __align__(16) unsigned short Bs[3 * SBUF];   // 24 KB

    int tid  = threadIdx.x;
    int lane = tid & 63;
    int wave = tid >> 6;
    int wm   = (wave >> 1) * 64;
    int wn   = (wave & 1) * 64;
    int l15  = lane & 15;
    int quad = lane >> 4;

    // staging: lane l -> row (wave*16 + l>>2), dest slot l&3; source chunk
    // xor-swizzled so LDS slot s of row r holds global chunk s^(r&3).
    int r16 = lane >> 2;
    int sch = lane & 3;
    int gch = sch ^ (r16 & 3);

    const unsigned short* gA0 = A  + (size_t)(m0 + wave * 16 + r16) * KDIM + gch * 8;
    const unsigned short* gA1 = gA0 + (size_t)64 * KDIM;
    const unsigned short* gB0 = Bm + (size_t)(n0 + wave * 16 + r16) * KDIM + gch * 8;
    const unsigned short* gB1 = gB0 + (size_t)64 * KDIM;

    // LDS dest offsets within one buffer (ushort units)
    int dA0 = (wave * 16) * BK;
    int dA1 = (64 + wave * 16) * BK;
    int dB0 = dA0;
    int dB1 = dA1;

#define STAGE(kk, bo) do {                                        \
        GLOAD_LDS16(gA0 + (kk) * BK, &As[(bo) + dA0]);            \
        GLOAD_LDS16(gA1 + (kk) * BK, &As[(bo) + dA1]);            \
        GLOAD_LDS16(gB0 + (kk) * BK, &Bs[(bo) + dB0]);            \
        GLOAD_LDS16(gB1 + (kk) * BK, &Bs[(bo) + dB1]);            \
    } while (0)

    // fragment LDS offsets (ushort units, loop-invariant): row rr, slot quad^(rr&3)
    int aoff[4], boff[4];
    int sl = quad ^ (l15 & 3);
#pragma unroll
    for (int im = 0; im < 4; im++)
        aoff[im] = (wm + im * 16 + l15) * BK + sl * 8;
#pragma unroll
    for (int jn = 0; jn < 4; jn++)
        boff[jn] = (wn + jn * 16 + l15) * BK + sl * 8;

    floatx4 acc[4][4];
#pragma unroll
    for (int i = 0; i < 4; i++)
#pragma unroll
        for (int j = 0; j < 4; j++) acc[i][j] = (floatx4)0.0f;

    // prologue: tiles 0 and 1 in flight
    STAGE(0, 0);
    STAGE(1, SBUF);

#pragma unroll
    for (int k = 0; k < KIT; ++k) {
        // wait for tile k only (oldest 4 loads); keep tile k+1 in flight.
        if (k < KIT - 1) asm volatile("s_waitcnt vmcnt(4)" ::: "memory");
        else             asm volatile("s_waitcnt vmcnt(0)" ::: "memory");
        __builtin_amdgcn_s_barrier();   // raw barrier: no implicit vmcnt drain

        // prefetch tile k+2 into the buffer freed by tile k-1
        if (k + 2 < KIT) STAGE(k + 2, ((k + 2) % 3) * SBUF);

        const int cb = (k % 3) * SBUF;
        bf16x8 af[4], bf[4];
#pragma unroll
        for (int im = 0; im < 4; im++)
            af[im] = __builtin_bit_cast(bf16x8, *(const uint4*)&As[cb + aoff[im]]);
#pragma unroll
        for (int jn = 0; jn < 4; jn++)
            bf[jn] = __builtin_bit_cast(bf16x8, *(const uint4*)&Bs[cb + boff[jn]]);
#pragma unroll
        for (int im = 0; im < 4; im++)
#pragma unroll
            for (int jn = 0; jn < 4; jn++)
                acc[im][jn] = __builtin_amdgcn_mfma_f32_16x16x32_bf16(
                    af[im], bf[jn], acc[im][jn], 0, 0, 0);
    }
#undef STAGE

    // epilogue: C/D layout col = lane&15, row = quad*4 + reg   [m89/m91]
#pragma unroll
    for (int im = 0; im < 4; im++)
#pragma unroll
        for (int jn = 0; jn < 4; jn++) {
            int c = n0 + wn + jn * 16 + l15;
#pragma unroll
            for (int r = 0; r < 4; r++) {
                int m = m0 + wm + im * 16 + quad * 4 + r;
                size_t idx = (size_t)m * N_ + c;
                float v = acc[im][jn][r];
                if (mode) v = 2.0f * v - bf2f(X[idx]);
                C[idx] = f2bf(v);
            }
        }
}

// ---- K3: projection as MFMA GEMM ----
// Per batch: C[o=64][n=tq=32768] = Wb[64][192] @ D[192][n].
// v2 staging: coalesced global loads (lanes contiguous in n), 8x8 u16
// transpose in registers (v_perm_b32), ds_write_b128 into a 16B-chunk
// XOR-swizzled [256 n][64 j] tile (chunk' = octet ^ ((n>>3)&7)) -- same
// involution applied on read, so both sides spread all 8 bank-quads.
__global__ __launch_bounds__(256) void proj(
    const unsigned short* __restrict__ xb,
    const unsigned short* __restrict__ z1b,
    const unsigned short* __restrict__ z2b,
    const unsigned short* __restrict__ Wb,
    float* __restrict__ out)
{
    __shared__ __align__(16) unsigned short Ds[256 * 64];   // 32 KB

    int b  = blockIdx.y;
    int n0 = blockIdx.x * 256;
    int tid  = threadIdx.x;
    int lane = tid & 63;
    int wave = tid >> 6;
    int l15  = lane & 15;
    int quad = lane >> 4;

    size_t boff = (size_t)b * M_ * N_ + n0;
    const unsigned short* zp[3] = { xb + boff, z1b + boff, z2b + boff };

    // A-operand (W) fragments in registers: wave w -> o-tile [w*16, w*16+16)
    bf16x8 wf[6];
#pragma unroll
    for (int kc = 0; kc < 6; kc++)
        wf[kc] = __builtin_bit_cast(bf16x8,
            *(const uint4*)(Wb + (size_t)(wave * 16 + l15) * 192 + kc * 32 + quad * 8));

    floatx4 acc[16];
#pragma unroll
    for (int i = 0; i < 16; i++) acc[i] = (floatx4)0.0f;

    // staging map: thread owns channel octet c0..c0+7  x  n-run nl0..nl0+7
    int c0  = (tid >> 5) * 8;          // channel (j) octet base
    int nl0 = (tid & 31) * 8;          // local n base
    int swz = ((tid >> 5) ^ (tid & 7)) & 7;   // write chunk (same for all 8 rows)

    uintx4 v[8];
    // prefetch round 0 (z0 = x)
#pragma unroll
    for (int r = 0; r < 8; r++)
        v[r] = *(const uintx4*)(zp[0] + (size_t)(c0 + r) * (T_ * N_) + nl0);

#pragma unroll
    for (int a = 0; a < 3; a++) {
        // prev round's ds_reads done + our prefetch drained (implicit vmcnt(0))
        __syncthreads();

        // in-register 8x8 u16 transpose + swizzled b128 writes
#pragma unroll
        for (int i = 0; i < 8; i++) {
            const int wi = i >> 1;
            const unsigned sel = (i & 1) ? 0x07060302u : 0x05040100u;
            uintx4 t;
            t[0] = __builtin_amdgcn_perm(v[1][wi], v[0][wi], sel);
            t[1] = __builtin_amdgcn_perm(v[3][wi], v[2][wi], sel);
            t[2] = __builtin_amdgcn_perm(v[5][wi], v[4][wi], sel);
            t[3] = __builtin_amdgcn_perm(v[7][wi], v[6][wi], sel);
            *(uintx4*)&Ds[(size_t)(nl0 + i) * 64 + swz * 8] = t;
        }
        __syncthreads();   // writes visible

        // issue next round's global loads early; they complete under the
        // MFMA phase and are drained by next round's __syncthreads (T14).
        if (a < 2) {
#pragma unroll
            for (int r = 0; r < 8; r++)
                v[r] = *(const uintx4*)(zp[a + 1] + (size_t)(c0 + r) * (T_ * N_) + nl0);
        }

#pragma unroll
        for (int ks = 0; ks < 2; ks++) {
            const int kc = a * 2 + ks;
#pragma unroll
            for (int nt = 0; nt < 16; nt++) {
                int n  = nt * 16 + l15;
                int ch = ((ks * 4 + quad) ^ ((n >> 3) & 7)) & 7;
                bf16x8 bfr = __builtin_bit_cast(bf16x8,
                    *(const uint4*)&Ds[(size_t)n * 64 + ch * 8]);
                acc[nt] = __builtin_amdgcn_mfma_f32_16x16x32_bf16(
                    wf[kc], bfr, acc[nt], 0, 0, 0);
            }
        }
    }

    // epilogue: col(l15) = n, row(quad*4+r) = o within wave's 16-tile
    float* ob = out + (size_t)b * COUT * (T_ * N_);
#pragma unroll
    for (int nt = 0; nt < 16; nt++) {
        int n = n0 + nt * 16 + l15;
#pragma unroll
        for (int r = 0; r < 4; r++) {
            int o = wave * 16 + quad * 4 + r;
            ob[(size_t)o * (T_ * N_) + n] = acc[nt][r];
        }
    }
}

extern "C" void kernel_launch(void* const* d_in, const int* in_sizes, int n_in,
                              void* d_out, int out_size, void* d_ws, size_t ws_size,
                              hipStream_t stream) {
    const float* x  = (const float*)d_in[0];
    const float* La = (const float*)d_in[1];
    const float* W  = (const float*)d_in[2];
    float* out = (float*)d_out;

    const size_t n_x  = (size_t)B_ * CIN * T_ * N_;   // 33,554,432
    const size_t n_La = (size_t)B_ * N_ * N_;         //  4,194,304

    char* ws = (char*)d_ws;
    unsigned short* xb  = (unsigned short*)ws;                         // 64 MiB
    unsigned short* Lab = (unsigned short*)(ws + n_x * 2);             //  8 MiB
    unsigned short* z1b = (unsigned short*)(ws + n_x * 2 + n_La * 2);  // 64 MiB
    unsigned short* z2b = (unsigned short*)(ws + n_x * 4 + n_La * 2);  // 64 MiB
    unsigned short* Wb  = (unsigned short*)(ws + n_x * 6 + n_La * 2);  // 24 KiB

    cvt_f32_bf16<<<(int)(n_x / 2048),  256, 0, stream>>>(x,  xb,  (int)n_x);
    cvt_f32_bf16<<<(int)(n_La / 2048), 256, 0, stream>>>(La, Lab, (int)n_La);
    pack_w<<<48, 256, 0, stream>>>(W, Wb);

    dim3 gg(N_ / BN, M_ / BM, B_);   // (4, 32, 16)
    gemm_bt<<<gg, 256, 0, stream>>>(xb,  Lab, z1b, xb, 0);
    gemm_bt<<<gg, 256, 0, stream>>>(z1b, Lab, z2b, xb, 1);

    dim3 gp((T_ * N_) / 256, B_);    // (128, 16)
    proj<<<gp, 256, 0, stream>>>(xb, z1b, z2b, Wb, out);
}

// Round 2
// 424.650 us; speedup vs baseline: 1.1050x; 1.0395x over previous
//
#include <hip/hip_runtime.h>
#include <hip/hip_bf16.h>

// Problem dims (fixed by reference):
//   x:  [B=16, c_in=64, T=64, N=512] fp32
//   La: [B=16, N=512, N=512] fp32
//   W:  [c_out=64, K*c_in=192] fp32
//   out:[B, 64, T, N] fp32
// Math: out[b,o,t,q] = sum_{c,k} W[o, c*3+k] * z_k[b,c,t,q]
//   z0 = x ; z1 = X @ La^T (rows ct, reduce n) ; z2 = 2*(z1 @ La^T) - x

#define B_   16
#define CIN  64
#define T_   64
#define N_   512
#define M_   4096   // CIN*T_ rows per batch
#define KDIM 512
#define COUT 64

typedef __bf16 bf16x8 __attribute__((ext_vector_type(8)));
typedef float  floatx4 __attribute__((ext_vector_type(4)));

__device__ __forceinline__ float bf2f(unsigned short u) {
    unsigned int v = ((unsigned int)u) << 16;
    return __builtin_bit_cast(float, v);
}
__device__ __forceinline__ unsigned short f2bf(float f) {
    unsigned int u = __builtin_bit_cast(unsigned int, f);
    unsigned int lsb = (u >> 16) & 1u;
    u += 0x7fffu + lsb;           // round-to-nearest-even
    return (unsigned short)(u >> 16);
}

// async global->LDS, 16B per lane; LDS dest = wave-uniform base + lane*16
#define GLOAD_LDS16(gp, lp)                                                  \
    __builtin_amdgcn_global_load_lds(                                        \
        (const __attribute__((address_space(1))) void*)(gp),                 \
        (__attribute__((address_space(3))) void*)(lp), 16, 0, 0)

// ---- K0a/K0b: fp32 -> bf16 convert, 8 elems/thread ----
__global__ __launch_bounds__(256) void cvt_f32_bf16(
    const float* __restrict__ src, unsigned short* __restrict__ dst, int n)
{
    int i = (blockIdx.x * 256 + threadIdx.x) * 8;
    if (i + 8 <= n) {
        float4 a = *(const float4*)(src + i);
        float4 b = *(const float4*)(src + i + 4);
        union { unsigned short s[8]; uint4 u; } o;
        o.s[0] = f2bf(a.x); o.s[1] = f2bf(a.y); o.s[2] = f2bf(a.z); o.s[3] = f2bf(a.w);
        o.s[4] = f2bf(b.x); o.s[5] = f2bf(b.y); o.s[6] = f2bf(b.z); o.s[7] = f2bf(b.w);
        *(uint4*)(dst + i) = o.u;
    }
}

// ---- K0c: repack W[o][c*3+k] -> Wb[o][j=k*64+c] bf16 (A-operand layout) ----
__global__ __launch_bounds__(256) void pack_w(
    const float* __restrict__ W, unsigned short* __restrict__ Wb)
{
    int idx = threadIdx.x + blockIdx.x * 256;   // idx = o*192 + j
    if (idx < 64 * 192) {
        int o = idx / 192, j = idx % 192;
        int c = j & 63, k = j >> 6;
        Wb[idx] = f2bf(W[o * 192 + c * 3 + k]);
    }
}

// ---- K1/K2: batched bf16 NT-GEMM  C[m][q] = sum_n A[m][n]*Bm[q][n] ----
// v3: triple-buffer + counted vmcnt (v2) PLUS:
//  - XCD-aware 1-D block remap: each XCD owns 2 batches; the 4 n-blocks
//    sharing an A-panel are temporally adjacent on the same XCD ->
//    B stays L2-resident, A-panel re-reads become L2 hits.
//  - chunk swizzle uses (row>>1)&3 (not row&3): bank group of a b128 read
//    is (row&1)*16 + slot*4, so the new XOR makes each 8-lane run hit 8
//    distinct bank-quads -> 2 lanes/bank = conflict-free.
#define BM 128
#define BN 128
#define BK 32
#define KIT  (KDIM / BK)     // 16 K-steps
#define SBUF (BM * BK)       // 4096 ushorts per buffer per matrix

__global__ __launch_bounds__(256) void gemm_bt(
    const unsigned short* __restrict__ A,
    const unsigned short* __restrict__ Bm,
    unsigned short* __restrict__ C,
    const unsigned short* __restrict__ X,
    int mode)
{
    // XCD-aware decode: h%8 = XCD (round-robin heuristic); each XCD gets
    // 2 full batches (idx>>7), 128 blocks each: local = 4 n-blocks x 32 m.
    int h     = blockIdx.x;
    int g     = h & 7;
    int idx   = h >> 3;                 // 0..255
    int batch = g * 2 + (idx >> 7);
    int local = idx & 127;
    int n0    = (local & 3) * BN;
    int m0    = (local >> 2) * BM;

    A  += (size_t)batch * M_ * KDIM;
    Bm += (size_t)batch * N_ * KDIM;
    C  += (size_t)batch * M_ * N_;
    X  += (size_t)batch * M_ * N_;

    __shared__ __align__(16) unsigned short As[3 * SBUF];   // 24 KB
    __shared__ __align__(16) unsigned short Bs[3 * SBUF];   // 24 KB

    int tid  = threadIdx.x;
    int lane = tid & 63;
    int wave = tid >> 6;
    int wm   = (wave >> 1) * 64;
    int wn   = (wave & 1) * 64;
    int l15  = lane & 15;
    int quad = lane >> 4;

    // staging: lane l -> row (wave*16 + l>>2), dest slot l&3; source chunk
    // xor-swizzled so LDS slot s of row r holds global chunk s^((r>>1)&3).
    int r16 = lane >> 2;
    int sch = lane & 3;
    int gch = sch ^ ((r16 >> 1) & 3);

    const unsigned short* gA0 = A  + (size_t)(m0 + wave * 16 + r16) * KDIM + gch * 8;
    const unsigned short* gA1 = gA0 + (size_t)64 * KDIM;
    const unsigned short* gB0 = Bm + (size_t)(n0 + wave * 16 + r16) * KDIM + gch * 8;
    const unsigned short* gB1 = gB0 + (size_t)64 * KDIM;

    // LDS dest offsets within one buffer (ushort units)
    int dA0 = (wave * 16) * BK;
    int dA1 = (64 + wave * 16) * BK;
    int dB0 = dA0;
    int dB1 = dA1;

#define STAGE(kk, bo) do {                                        \
        GLOAD_LDS16(gA0 + (kk) * BK, &As[(bo) + dA0]);            \
        GLOAD_LDS16(gA1 + (kk) * BK, &As[(bo) + dA1]);            \
        GLOAD_LDS16(gB0 + (kk) * BK, &Bs[(bo) + dB0]);            \
        GLOAD_LDS16(gB1 + (kk) * BK, &Bs[(bo) + dB1]);            \
    } while (0)

    // fragment LDS offsets (ushort units, loop-invariant):
    // row rr = base16 + l15 -> (rr>>1)&3 == (l15>>1)&3 (base16 % 16 == 0)
    int aoff[4], boff[4];
    int sl = quad ^ ((l15 >> 1) & 3);
#pragma unroll
    for (int im = 0; im < 4; im++)
        aoff[im] = (wm + im * 16 + l15) * BK + sl * 8;
#pragma unroll
    for (int jn = 0; jn < 4; jn++)
        boff[jn] = (wn + jn * 16 + l15) * BK + sl * 8;

    floatx4 acc[4][4];
#pragma unroll
    for (int i = 0; i < 4; i++)
#pragma unroll
        for (int j = 0; j < 4; j++) acc[i][j] = (floatx4)0.0f;

    // prologue: tiles 0 and 1 in flight
    STAGE(0, 0);
    STAGE(1, SBUF);

#pragma unroll
    for (int k = 0; k < KIT; ++k) {
        // wait for tile k only (oldest 4 loads); keep tile k+1 in flight.
        if (k < KIT - 1) asm volatile("s_waitcnt vmcnt(4)" ::: "memory");
        else             asm volatile("s_waitcnt vmcnt(0)" ::: "memory");
        __builtin_amdgcn_s_barrier();   // raw barrier: no implicit vmcnt drain

        // prefetch tile k+2 into the buffer freed by tile k-1
        if (k + 2 < KIT) STAGE(k + 2, ((k + 2) % 3) * SBUF);

        const int cb = (k % 3) * SBUF;
        bf16x8 af[4], bf[4];
#pragma unroll
        for (int im = 0; im < 4; im++)
            af[im] = __builtin_bit_cast(bf16x8, *(const uint4*)&As[cb + aoff[im]]);
#pragma unroll
        for (int jn = 0; jn < 4; jn++)
            bf[jn] = __builtin_bit_cast(bf16x8, *(const uint4*)&Bs[cb + boff[jn]]);
#pragma unroll
        for (int im = 0; im < 4; im++)
#pragma unroll
            for (int jn = 0; jn < 4; jn++)
                acc[im][jn] = __builtin_amdgcn_mfma_f32_16x16x32_bf16(
                    af[im], bf[jn], acc[im][jn], 0, 0, 0);
    }
#undef STAGE

    // epilogue: C/D layout col = lane&15, row = quad*4 + reg   [m89/m91]
#pragma unroll
    for (int im = 0; im < 4; im++)
#pragma unroll
        for (int jn = 0; jn < 4; jn++) {
            int c = n0 + wn + jn * 16 + l15;
#pragma unroll
            for (int r = 0; r < 4; r++) {
                int m = m0 + wm + im * 16 + quad * 4 + r;
                size_t idx2 = (size_t)m * N_ + c;
                float v = acc[im][jn][r];
                if (mode) v = 2.0f * v - bf2f(X[idx2]);
                C[idx2] = f2bf(v);
            }
        }
}

// ---- K3: projection as MFMA GEMM ----
// Per batch: C[o=64][n=tq=32768] = Wb[64][192] @ D[192][n],
// D rows j=k*64+c -> z_k row c. B-fragments need D^T[n][j]: stage 32j x 256n
// chunks transposed in LDS (pitch 40 -> 16B-aligned b128 reads, 2-way max).
// (round-0 proven version; the b128-write variant hit a pigeonhole 4-way
// write conflict on the [.][64] layout and regressed ~13us)
#define PJ_PITCH 40

__global__ __launch_bounds__(256) void proj(
    const unsigned short* __restrict__ xb,
    const unsigned short* __restrict__ z1b,
    const unsigned short* __restrict__ z2b,
    const unsigned short* __restrict__ Wb,
    float* __restrict__ out)
{
    __shared__ __align__(16) unsigned short Ds[256 * PJ_PITCH];   // 20 KB

    int b  = blockIdx.y;
    int n0 = blockIdx.x * 256;
    int tid  = threadIdx.x;
    int lane = tid & 63;
    int wave = tid >> 6;
    int l15  = lane & 15;
    int quad = lane >> 4;

    size_t boff = (size_t)b * M_ * N_ + n0;
    const unsigned short* zp[3] = { xb + boff, z1b + boff, z2b + boff };

    // A-operand (W) fragments in registers: wave w -> o-tile [w*16, w*16+16)
    bf16x8 wf[6];
#pragma unroll
    for (int kc = 0; kc < 6; kc++)
        wf[kc] = __builtin_bit_cast(bf16x8,
            *(const uint4*)(Wb + (size_t)(wave * 16 + l15) * 192 + kc * 32 + quad * 8));

    floatx4 acc[16];
#pragma unroll
    for (int i = 0; i < 16; i++) acc[i] = (floatx4)0.0f;

    // staging mapping: row jl = tid&31 (j within 32-chunk), col group tid>>5
    int jl  = tid & 31;
    int nc0 = (tid >> 5) * 8;

    for (int kc = 0; kc < 6; kc++) {
        const unsigned short* src =
            zp[kc >> 1] + (size_t)((kc & 1) * 32 + jl) * (T_ * N_) + nc0;
        uint4 v[4];
#pragma unroll
        for (int u = 0; u < 4; u++) v[u] = *(const uint4*)(src + u * 64);

        __syncthreads();   // previous chunk's compute done before overwrite
#pragma unroll
        for (int u = 0; u < 4; u++) {
            unsigned short* d = &Ds[(size_t)(nc0 + u * 64) * PJ_PITCH + jl];
            unsigned int w0 = v[u].x, w1 = v[u].y, w2 = v[u].z, w3 = v[u].w;
            d[0 * PJ_PITCH] = (unsigned short)w0;
            d[1 * PJ_PITCH] = (unsigned short)(w0 >> 16);
            d[2 * PJ_PITCH] = (unsigned short)w1;
            d[3 * PJ_PITCH] = (unsigned short)(w1 >> 16);
            d[4 * PJ_PITCH] = (unsigned short)w2;
            d[5 * PJ_PITCH] = (unsigned short)(w2 >> 16);
            d[6 * PJ_PITCH] = (unsigned short)w3;
            d[7 * PJ_PITCH] = (unsigned short)(w3 >> 16);
        }
        __syncthreads();

#pragma unroll
        for (int nt = 0; nt < 16; nt++) {
            bf16x8 bfr = __builtin_bit_cast(bf16x8,
                *(const uint4*)(&Ds[(size_t)(nt * 16 + l15) * PJ_PITCH + quad * 8]));
            acc[nt] = __builtin_amdgcn_mfma_f32_16x16x32_bf16(wf[kc], bfr, acc[nt], 0, 0, 0);
        }
    }

    // epilogue: col(l15) = n, row(quad*4+r) = o within wave's 16-tile
    float* ob = out + (size_t)b * COUT * (T_ * N_);
#pragma unroll
    for (int nt = 0; nt < 16; nt++) {
        int n = n0 + nt * 16 + l15;
#pragma unroll
        for (int r = 0; r < 4; r++) {
            int o = wave * 16 + quad * 4 + r;
            ob[(size_t)o * (T_ * N_) + n] = acc[nt][r];
        }
    }
}

extern "C" void kernel_launch(void* const* d_in, const int* in_sizes, int n_in,
                              void* d_out, int out_size, void* d_ws, size_t ws_size,
                              hipStream_t stream) {
    const float* x  = (const float*)d_in[0];
    const float* La = (const float*)d_in[1];
    const float* W  = (const float*)d_in[2];
    float* out = (float*)d_out;

    const size_t n_x  = (size_t)B_ * CIN * T_ * N_;   // 33,554,432
    const size_t n_La = (size_t)B_ * N_ * N_;         //  4,194,304

    char* ws = (char*)d_ws;
    unsigned short* xb  = (unsigned short*)ws;                         // 64 MiB
    unsigned short* Lab = (unsigned short*)(ws + n_x * 2);             //  8 MiB
    unsigned short* z1b = (unsigned short*)(ws + n_x * 2 + n_La * 2);  // 64 MiB
    unsigned short* z2b = (unsigned short*)(ws + n_x * 4 + n_La * 2);  // 64 MiB
    unsigned short* Wb  = (unsigned short*)(ws + n_x * 6 + n_La * 2);  // 24 KiB

    cvt_f32_bf16<<<(int)(n_x / 2048),  256, 0, stream>>>(x,  xb,  (int)n_x);
    cvt_f32_bf16<<<(int)(n_La / 2048), 256, 0, stream>>>(La, Lab, (int)n_La);
    pack_w<<<48, 256, 0, stream>>>(W, Wb);

    // XCD-aware 1-D grid: 2048 blocks, decoded inside gemm_bt
    gemm_bt<<<2048, 256, 0, stream>>>(xb,  Lab, z1b, xb, 0);
    gemm_bt<<<2048, 256, 0, stream>>>(z1b, Lab, z2b, xb, 1);

    dim3 gp((T_ * N_) / 256, B_);    // (128, 16)
    proj<<<gp, 256, 0, stream>>>(xb, z1b, z2b, Wb, out);
}